// Round 1
// baseline (1028.238 us; speedup 1.0000x reference)
//
#include <hip/hip_runtime.h>
#include <math.h>

// MambaMIL fp32 baseline.
// Pipeline: proj+relu -> 2x { LN -> W_in GEMM -> causal conv4+silu -> W_x GEMM
//           -> W_dt GEMM+softplus -> chunked selective scan -> *silu(z) -> W_out GEMM }
//           -> +res -> LN -> attn scores -> softmax -> weighted pool -> head.

#define LSEQ 4096
#define DMODEL 512
#define DINNER 1024
#define DSTATE 16
#define DTRANK 32
#define NCHUNK 64
#define CHLEN 64

enum { ACT_NONE = 0, ACT_RELU = 1, ACT_SOFTPLUS = 2 };

__device__ __forceinline__ float wave_sum(float v) {
#pragma unroll
  for (int off = 32; off > 0; off >>= 1) v += __shfl_xor(v, off, 64);
  return v;
}
__device__ __forceinline__ float wave_max(float v) {
#pragma unroll
  for (int off = 32; off > 0; off >>= 1) v = fmaxf(v, __shfl_xor(v, off, 64));
  return v;
}
__device__ __forceinline__ float siluf(float x) { return x / (1.f + expf(-x)); }

// ---------------- tiled fp32 GEMM: C = act(A @ B + bias) ----------------
// A: M x K (row stride lda), B: K x N row-major, C: M x N dense.
template <int BM, int BN, int BK, int TM, int TN, int ACT, bool BIAS>
__global__ __launch_bounds__(256) void gemm_f32(
    const float* __restrict__ A, int lda, const float* __restrict__ B,
    const float* __restrict__ bias, float* __restrict__ C, int M, int N, int K) {
  constexpr int TX = BN / TN;
  constexpr int TY = BM / TM;
  static_assert(TX * TY == 256, "bad cfg");
  __shared__ float As[BK][BM + 4];  // +4 keeps rows 16B-aligned, shifts banks
  __shared__ float Bs[BK][BN];
  const int tid = threadIdx.x;
  const int tx = tid % TX, ty = tid / TX;
  const int bm = blockIdx.y * BM, bn = blockIdx.x * BN;
  float acc[TM][TN];
#pragma unroll
  for (int i = 0; i < TM; ++i)
#pragma unroll
    for (int j = 0; j < TN; ++j) acc[i][j] = 0.f;

  for (int k0 = 0; k0 < K; k0 += BK) {
#pragma unroll
    for (int i = tid; i < BM * BK / 4; i += 256) {
      int r = i / (BK / 4), c4 = i % (BK / 4);
      const float4 v = *(const float4*)&A[(size_t)(bm + r) * lda + k0 + c4 * 4];
      As[c4 * 4 + 0][r] = v.x;
      As[c4 * 4 + 1][r] = v.y;
      As[c4 * 4 + 2][r] = v.z;
      As[c4 * 4 + 3][r] = v.w;
    }
#pragma unroll
    for (int i = tid; i < BK * BN / 4; i += 256) {
      int r = i / (BN / 4), c4 = i % (BN / 4);
      *(float4*)&Bs[r][c4 * 4] = *(const float4*)&B[(size_t)(k0 + r) * N + bn + c4 * 4];
    }
    __syncthreads();
#pragma unroll
    for (int k = 0; k < BK; ++k) {
      float a[TM], b[TN];
#pragma unroll
      for (int i = 0; i < TM; i += 4) {
        const float4 t = *(const float4*)&As[k][ty * TM + i];
        a[i] = t.x; a[i + 1] = t.y; a[i + 2] = t.z; a[i + 3] = t.w;
      }
#pragma unroll
      for (int j = 0; j < TN; j += 4) {
        const float4 t = *(const float4*)&Bs[k][tx * TN + j];
        b[j] = t.x; b[j + 1] = t.y; b[j + 2] = t.z; b[j + 3] = t.w;
      }
#pragma unroll
      for (int i = 0; i < TM; ++i)
#pragma unroll
        for (int j = 0; j < TN; ++j) acc[i][j] = fmaf(a[i], b[j], acc[i][j]);
    }
    __syncthreads();
  }
#pragma unroll
  for (int i = 0; i < TM; ++i) {
    const int row = bm + ty * TM + i;
#pragma unroll
    for (int j = 0; j < TN; ++j) {
      float v = acc[i][j];
      if (BIAS) v += bias[bn + tx * TN + j];
      if (ACT == ACT_RELU) v = fmaxf(v, 0.f);
      if (ACT == ACT_SOFTPLUS) v = fmaxf(v, 0.f) + log1pf(expf(-fabsf(v)));
      acc[i][j] = v;
    }
#pragma unroll
    for (int j = 0; j < TN; j += 4) {
      float4 t;
      t.x = acc[i][j]; t.y = acc[i][j + 1]; t.z = acc[i][j + 2]; t.w = acc[i][j + 3];
      *(float4*)&C[(size_t)row * N + bn + tx * TN + j] = t;
    }
  }
}

// ---------------- skinny GEMM for W_x: 4096x1024 @ 1024x64 ----------------
__global__ __launch_bounds__(256) void gemm_skinny64(
    const float* __restrict__ A, const float* __restrict__ B, float* __restrict__ C) {
  __shared__ float As[4][DINNER];
  const int r = threadIdx.x >> 6;
  const int j = threadIdx.x & 63;
  const int row0 = blockIdx.x * 4;
  for (int i = threadIdx.x; i < DINNER; i += 256) {  // i indexes float4s (4 rows x 256)
    *(float4*)&As[i >> 8][(i & 255) * 4] =
        *(const float4*)&A[(size_t)(row0 + (i >> 8)) * DINNER + (i & 255) * 4];
  }
  __syncthreads();
  float a0 = 0.f, a1 = 0.f, a2 = 0.f, a3 = 0.f;
  for (int k = 0; k < DINNER; k += 4) {
    a0 = fmaf(As[r][k + 0], B[(size_t)(k + 0) * 64 + j], a0);
    a1 = fmaf(As[r][k + 1], B[(size_t)(k + 1) * 64 + j], a1);
    a2 = fmaf(As[r][k + 2], B[(size_t)(k + 2) * 64 + j], a2);
    a3 = fmaf(As[r][k + 3], B[(size_t)(k + 3) * 64 + j], a3);
  }
  C[(size_t)(row0 + r) * 64 + j] = (a0 + a1) + (a2 + a3);
}

// ---------------- LayerNorm over 512 cols; optional fused residual add ----
__global__ __launch_bounds__(256) void layernorm_k(
    const float* __restrict__ x, const float* __restrict__ res,
    const float* __restrict__ w, const float* __restrict__ b, float* __restrict__ out) {
  const int wave = threadIdx.x >> 6, lane = threadIdx.x & 63;
  const int row = blockIdx.x * 4 + wave;
  const size_t base = (size_t)row * DMODEL;
  float4 v0 = *(const float4*)&x[base + lane * 4];
  float4 v1 = *(const float4*)&x[base + 256 + lane * 4];
  if (res != nullptr) {
    const float4 r0 = *(const float4*)&res[base + lane * 4];
    const float4 r1 = *(const float4*)&res[base + 256 + lane * 4];
    v0.x += r0.x; v0.y += r0.y; v0.z += r0.z; v0.w += r0.w;
    v1.x += r1.x; v1.y += r1.y; v1.z += r1.z; v1.w += r1.w;
  }
  float s = (v0.x + v0.y) + (v0.z + v0.w) + (v1.x + v1.y) + (v1.z + v1.w);
  const float mean = wave_sum(s) * (1.f / DMODEL);
  const float d0 = v0.x - mean, d1 = v0.y - mean, d2 = v0.z - mean, d3 = v0.w - mean;
  const float d4 = v1.x - mean, d5 = v1.y - mean, d6 = v1.z - mean, d7 = v1.w - mean;
  float q = (d0 * d0 + d1 * d1) + (d2 * d2 + d3 * d3) + (d4 * d4 + d5 * d5) + (d6 * d6 + d7 * d7);
  const float rstd = rsqrtf(wave_sum(q) * (1.f / DMODEL) + 1e-5f);
  const float4 w0 = *(const float4*)&w[lane * 4];
  const float4 w1 = *(const float4*)&w[256 + lane * 4];
  const float4 b0 = *(const float4*)&b[lane * 4];
  const float4 b1 = *(const float4*)&b[256 + lane * 4];
  float4 o0, o1;
  o0.x = fmaf(d0 * rstd, w0.x, b0.x);
  o0.y = fmaf(d1 * rstd, w0.y, b0.y);
  o0.z = fmaf(d2 * rstd, w0.z, b0.z);
  o0.w = fmaf(d3 * rstd, w0.w, b0.w);
  o1.x = fmaf(d4 * rstd, w1.x, b1.x);
  o1.y = fmaf(d5 * rstd, w1.y, b1.y);
  o1.z = fmaf(d6 * rstd, w1.z, b1.z);
  o1.w = fmaf(d7 * rstd, w1.w, b1.w);
  *(float4*)&out[base + lane * 4] = o0;
  *(float4*)&out[base + 256 + lane * 4] = o1;
}

// ---------------- depthwise causal conv (D_CONV=4) + bias + silu ----------
__global__ __launch_bounds__(256) void conv_silu_k(
    const float* __restrict__ xz, const float* __restrict__ Wc,
    const float* __restrict__ bc, float* __restrict__ xc) {
  const int idx = blockIdx.x * 256 + threadIdx.x;
  const int d = idx & (DINNER - 1);
  const int t = idx >> 10;
  const float4 w = *(const float4*)&Wc[d * 4];
  float acc = bc[d];
  if (t >= 3) acc = fmaf(w.x, xz[(size_t)(t - 3) * 2 * DINNER + d], acc);
  if (t >= 2) acc = fmaf(w.y, xz[(size_t)(t - 2) * 2 * DINNER + d], acc);
  if (t >= 1) acc = fmaf(w.z, xz[(size_t)(t - 1) * 2 * DINNER + d], acc);
  acc = fmaf(w.w, xz[(size_t)t * 2 * DINNER + d], acc);
  xc[idx] = siluf(acc);
}

// ---------------- selective scan: 3-phase chunked linear recurrence -------
// Per (d,s): state' = exp(delta*A[d,s]) * state + delta*B[t,s]*x[t,d]
__global__ __launch_bounds__(256) void scan_phaseA(
    const float* __restrict__ delta, const float* __restrict__ xc,
    const float* __restrict__ xdbl, const float* __restrict__ A_log,
    float* __restrict__ chA, float* __restrict__ chB) {
  const int chunk = blockIdx.x >> 2;
  const int d = ((blockIdx.x & 3) << 8) + threadIdx.x;
  __shared__ float Bsh[CHLEN][DSTATE];
  for (int i = threadIdx.x; i < CHLEN * DSTATE; i += 256) {
    const int t = i >> 4, s = i & 15;
    Bsh[t][s] = xdbl[(size_t)(chunk * CHLEN + t) * 64 + 32 + s];
  }
  __syncthreads();
  float Av[DSTATE];
#pragma unroll
  for (int s = 0; s < DSTATE; ++s) Av[s] = -expf(A_log[d * DSTATE + s]);
  float aP[DSTATE], bP[DSTATE];
#pragma unroll
  for (int s = 0; s < DSTATE; ++s) { aP[s] = 1.f; bP[s] = 0.f; }
  for (int t = 0; t < CHLEN; ++t) {
    const int tt = chunk * CHLEN + t;
    const float dl = delta[(size_t)tt * DINNER + d];
    const float du = dl * xc[(size_t)tt * DINNER + d];
#pragma unroll
    for (int s = 0; s < DSTATE; ++s) {
      const float a = expf(dl * Av[s]);
      bP[s] = fmaf(a, bP[s], du * Bsh[t][s]);
      aP[s] *= a;
    }
  }
  const size_t base = (size_t)chunk * DINNER * DSTATE + (size_t)d * DSTATE;
#pragma unroll
  for (int s = 0; s < DSTATE; ++s) {
    chA[base + s] = aP[s];
    chB[base + s] = bP[s];
  }
}

__global__ __launch_bounds__(256) void scan_phaseB(
    const float* __restrict__ chA, const float* __restrict__ chB, float* __restrict__ s0) {
  const int i = blockIdx.x * 256 + threadIdx.x;  // = d*16 + s
  float st = 0.f;
  for (int c = 0; c < NCHUNK; ++c) {
    const size_t idx = (size_t)c * DINNER * DSTATE + i;
    s0[idx] = st;
    st = fmaf(chA[idx], st, chB[idx]);
  }
}

__global__ __launch_bounds__(256) void scan_phaseC(
    const float* __restrict__ delta, const float* __restrict__ xc,
    const float* __restrict__ xdbl, const float* __restrict__ A_log,
    const float* __restrict__ Dsk, const float* __restrict__ s0,
    const float* __restrict__ xz, float* __restrict__ y) {
  const int chunk = blockIdx.x >> 2;
  const int d = ((blockIdx.x & 3) << 8) + threadIdx.x;
  __shared__ float BCsh[CHLEN][2 * DSTATE];
  for (int i = threadIdx.x; i < CHLEN * 2 * DSTATE; i += 256) {
    const int t = i >> 5, s = i & 31;
    BCsh[t][s] = xdbl[(size_t)(chunk * CHLEN + t) * 64 + 32 + s];
  }
  __syncthreads();
  float Av[DSTATE];
#pragma unroll
  for (int s = 0; s < DSTATE; ++s) Av[s] = -expf(A_log[d * DSTATE + s]);
  float st[DSTATE];
  const size_t base = (size_t)chunk * DINNER * DSTATE + (size_t)d * DSTATE;
#pragma unroll
  for (int s = 0; s < DSTATE; ++s) st[s] = s0[base + s];
  const float Dv = Dsk[d];
  for (int t = 0; t < CHLEN; ++t) {
    const int tt = chunk * CHLEN + t;
    const float dl = delta[(size_t)tt * DINNER + d];
    const float xv = xc[(size_t)tt * DINNER + d];
    const float du = dl * xv;
    float yv = 0.f;
#pragma unroll
    for (int s = 0; s < DSTATE; ++s) {
      const float a = expf(dl * Av[s]);
      st[s] = fmaf(a, st[s], du * BCsh[t][s]);
      yv = fmaf(st[s], BCsh[t][DSTATE + s], yv);
    }
    const float zv = xz[(size_t)tt * 2 * DINNER + DINNER + d];
    y[(size_t)tt * DINNER + d] = (yv + xv * Dv) * siluf(zv);
  }
}

// ---------------- attention scores: tanh(h@Wa1+ba1)@Wa2+ba2 ---------------
__global__ __launch_bounds__(128) void attn_scores_k(
    const float* __restrict__ h, const float* __restrict__ Wa1,
    const float* __restrict__ ba1, const float* __restrict__ Wa2,
    const float* __restrict__ ba2, float* __restrict__ scores) {
  __shared__ float hs[DMODEL];
  const int t = blockIdx.x;
  const int j = threadIdx.x;
  *(float4*)&hs[j * 4] = *(const float4*)&h[(size_t)t * DMODEL + j * 4];
  __syncthreads();
  float a0 = 0.f, a1 = 0.f, a2 = 0.f, a3 = 0.f;
  for (int k = 0; k < DMODEL; k += 4) {
    a0 = fmaf(hs[k + 0], Wa1[(size_t)(k + 0) * 128 + j], a0);
    a1 = fmaf(hs[k + 1], Wa1[(size_t)(k + 1) * 128 + j], a1);
    a2 = fmaf(hs[k + 2], Wa1[(size_t)(k + 2) * 128 + j], a2);
    a3 = fmaf(hs[k + 3], Wa1[(size_t)(k + 3) * 128 + j], a3);
  }
  float v = tanhf(((a0 + a1) + (a2 + a3)) + ba1[j]) * Wa2[j];
  v = wave_sum(v);
  __shared__ float red[2];
  if ((j & 63) == 0) red[j >> 6] = v;
  __syncthreads();
  if (j == 0) scores[t] = red[0] + red[1] + ba2[0];
}

__global__ __launch_bounds__(1024) void softmax_k(
    const float* __restrict__ s, float* __restrict__ aw) {
  const int tid = threadIdx.x;
  const int wave = tid >> 6, lane = tid & 63;
  const float4 v = *(const float4*)&s[tid * 4];
  float m = fmaxf(fmaxf(v.x, v.y), fmaxf(v.z, v.w));
  m = wave_max(m);
  __shared__ float redm[16];
  if (lane == 0) redm[wave] = m;
  __syncthreads();
  float bm = redm[0];
#pragma unroll
  for (int i = 1; i < 16; ++i) bm = fmaxf(bm, redm[i]);
  const float e0 = expf(v.x - bm), e1 = expf(v.y - bm);
  const float e2 = expf(v.z - bm), e3 = expf(v.w - bm);
  float sum = wave_sum((e0 + e1) + (e2 + e3));
  __shared__ float reds[16];
  if (lane == 0) reds[wave] = sum;
  __syncthreads();
  float Z = 0.f;
#pragma unroll
  for (int i = 0; i < 16; ++i) Z += reds[i];
  const float inv = 1.f / Z;
  float4 o;
  o.x = e0 * inv; o.y = e1 * inv; o.z = e2 * inv; o.w = e3 * inv;
  *(float4*)&aw[tid * 4] = o;
}

__global__ __launch_bounds__(256) void pool_partial_k(
    const float* __restrict__ aw, const float* __restrict__ h, float* __restrict__ part) {
  const int b = blockIdx.x;
  const int tid = threadIdx.x;
  float2 acc = make_float2(0.f, 0.f);
  for (int t = b * 64; t < b * 64 + 64; ++t) {
    const float w = aw[t];
    const float2 hv = *(const float2*)&h[(size_t)t * DMODEL + tid * 2];
    acc.x = fmaf(w, hv.x, acc.x);
    acc.y = fmaf(w, hv.y, acc.y);
  }
  *(float2*)&part[b * DMODEL + tid * 2] = acc;
}

__global__ __launch_bounds__(512) void pool_final_k(
    const float* __restrict__ part, const float* __restrict__ Wh,
    const float* __restrict__ bh, float* __restrict__ out) {
  const int d = threadIdx.x;
  float s = 0.f;
  for (int b = 0; b < 64; ++b) s += part[b * DMODEL + d];
  float v0 = wave_sum(s * Wh[d * 2 + 0]);
  float v1 = wave_sum(s * Wh[d * 2 + 1]);
  __shared__ float r0[8], r1[8];
  const int wave = d >> 6, lane = d & 63;
  if (lane == 0) { r0[wave] = v0; r1[wave] = v1; }
  __syncthreads();
  if (d == 0) {
    float o0 = bh[0], o1 = bh[1];
#pragma unroll
    for (int i = 0; i < 8; ++i) { o0 += r0[i]; o1 += r1[i]; }
    out[0] = o0;
    out[1] = o1;
  }
}

extern "C" void kernel_launch(void* const* d_in, const int* in_sizes, int n_in,
                              void* d_out, int out_size, void* d_ws, size_t ws_size,
                              hipStream_t stream) {
  const float* in_h = (const float*)d_in[0];
  const float* W_proj = (const float*)d_in[1];
  const float* b_proj = (const float*)d_in[2];
  const float* ln_w = (const float*)d_in[3];
  const float* ln_b = (const float*)d_in[4];
  const float* W_in = (const float*)d_in[5];
  const float* W_conv = (const float*)d_in[6];
  const float* b_conv = (const float*)d_in[7];
  const float* W_x = (const float*)d_in[8];
  const float* W_dt = (const float*)d_in[9];
  const float* b_dt = (const float*)d_in[10];
  const float* A_log = (const float*)d_in[11];
  const float* Dsk = (const float*)d_in[12];
  const float* W_out = (const float*)d_in[13];
  const float* norm_w = (const float*)d_in[14];
  const float* norm_b = (const float*)d_in[15];
  const float* Wa1 = (const float*)d_in[16];
  const float* ba1 = (const float*)d_in[17];
  const float* Wa2 = (const float*)d_in[18];
  const float* ba2 = (const float*)d_in[19];
  const float* Wh = (const float*)d_in[20];
  const float* bh = (const float*)d_in[21];
  float* out = (float*)d_out;

  float* ws = (float*)d_ws;
  size_t off = 0;
  auto alloc = [&](size_t n) {
    float* p = ws + off;
    off += (n + 63) & ~(size_t)63;
    return p;
  };
  float* res = alloc((size_t)LSEQ * DMODEL);
  float* hbuf = alloc((size_t)LSEQ * DMODEL);
  float* lnb = alloc((size_t)LSEQ * DMODEL);
  float* xz = alloc((size_t)LSEQ * 2 * DINNER);
  float* xc = alloc((size_t)LSEQ * DINNER);
  float* xdbl = alloc((size_t)LSEQ * 64);
  float* delta = alloc((size_t)LSEQ * DINNER);
  float* ybuf = alloc((size_t)LSEQ * DINNER);
  float* chA = alloc((size_t)DINNER * DSTATE * NCHUNK);
  float* chB = alloc((size_t)DINNER * DSTATE * NCHUNK);
  float* s0b = alloc((size_t)DINNER * DSTATE * NCHUNK);
  float* scores = alloc(LSEQ);
  float* aw = alloc(LSEQ);
  float* part = alloc((size_t)64 * DMODEL);
  (void)ws_size;

  // 1. h = relu(in @ W_proj + b_proj)  -> res (kept as residual)
  gemm_f32<128, 64, 16, 8, 4, ACT_RELU, true>
      <<<dim3(DMODEL / 64, LSEQ / 128), 256, 0, stream>>>(
          in_h, 1024, W_proj, b_proj, res, LSEQ, DMODEL, 1024);

  const float* cur = res;
  for (int l = 0; l < 2; ++l) {
    layernorm_k<<<LSEQ / 4, 256, 0, stream>>>(
        cur, nullptr, ln_w + l * DMODEL, ln_b + l * DMODEL, lnb);
    // xz = ln @ W_in
    gemm_f32<128, 128, 16, 8, 8, ACT_NONE, false>
        <<<dim3(2 * DINNER / 128, LSEQ / 128), 256, 0, stream>>>(
            lnb, DMODEL, W_in + (size_t)l * DMODEL * 2 * DINNER, nullptr, xz,
            LSEQ, 2 * DINNER, DMODEL);
    conv_silu_k<<<LSEQ * DINNER / 256, 256, 0, stream>>>(
        xz, W_conv + l * DINNER * 4, b_conv + l * DINNER, xc);
    gemm_skinny64<<<LSEQ / 4, 256, 0, stream>>>(
        xc, W_x + (size_t)l * DINNER * 64, xdbl);
    // delta = softplus(dt @ W_dt + b_dt); dt = xdbl[:, :32] (row stride 64)
    gemm_f32<128, 128, 16, 8, 8, ACT_SOFTPLUS, true>
        <<<dim3(DINNER / 128, LSEQ / 128), 256, 0, stream>>>(
            xdbl, 64, W_dt + (size_t)l * DTRANK * DINNER, b_dt + l * DINNER,
            delta, LSEQ, DINNER, DTRANK);
    const float* Al = A_log + (size_t)l * DINNER * DSTATE;
    scan_phaseA<<<NCHUNK * 4, 256, 0, stream>>>(delta, xc, xdbl, Al, chA, chB);
    scan_phaseB<<<DINNER * DSTATE / 256, 256, 0, stream>>>(chA, chB, s0b);
    scan_phaseC<<<NCHUNK * 4, 256, 0, stream>>>(
        delta, xc, xdbl, Al, Dsk + l * DINNER, s0b, xz, ybuf);
    // h = y @ W_out
    gemm_f32<128, 64, 16, 8, 4, ACT_NONE, false>
        <<<dim3(DMODEL / 64, LSEQ / 128), 256, 0, stream>>>(
            ybuf, DINNER, W_out + (size_t)l * DINNER * DMODEL, nullptr, hbuf,
            LSEQ, DMODEL, DINNER);
    cur = hbuf;
  }

  // h = LN(h + res) -> lnb
  layernorm_k<<<LSEQ / 4, 256, 0, stream>>>(cur, res, norm_w, norm_b, lnb);
  attn_scores_k<<<LSEQ, 128, 0, stream>>>(lnb, Wa1, ba1, Wa2, ba2, scores);
  softmax_k<<<1, 1024, 0, stream>>>(scores, aw);
  pool_partial_k<<<64, 256, 0, stream>>>(aw, lnb, part);
  pool_final_k<<<1, 512, 0, stream>>>(part, Wh, bh, out);
}

// Round 3
// 621.908 us; speedup vs baseline: 1.6534x; 1.6534x over previous
//
#include <hip/hip_runtime.h>
#include <math.h>

// MambaMIL: bf16-MFMA for the 3 big GEMMs (proj, W_in, W_out), fp32 elsewhere.
// R3 fix: gemm_bf16 LDS staging covered only half the k-tile (srow=tid>>1,
// sg=tid&1 -> 256 of 512 granules); lanes kg>=2 read uninitialized LDS -> NaN.
// Now each thread stages rows srow and srow+64, all 4 granules per row.

#define LSEQ 4096
#define DMODEL 512
#define DINNER 1024
#define DSTATE 16
#define DTRANK 32
#define NCHUNK 64
#define CHLEN 64

enum { ACT_NONE = 0, ACT_RELU = 1, ACT_SOFTPLUS = 2 };

typedef __attribute__((ext_vector_type(8))) short bf16x8;
typedef __attribute__((ext_vector_type(4))) float f32x4;

__device__ __forceinline__ float wave_sum(float v) {
#pragma unroll
  for (int off = 32; off > 0; off >>= 1) v += __shfl_xor(v, off, 64);
  return v;
}
__device__ __forceinline__ float wave_max(float v) {
#pragma unroll
  for (int off = 32; off > 0; off >>= 1) v = fmaxf(v, __shfl_xor(v, off, 64));
  return v;
}
__device__ __forceinline__ float siluf(float x) { return x / (1.f + expf(-x)); }

__device__ __forceinline__ ushort f2bf(float f) {
  union { float f; unsigned u; } c;
  c.f = f;
  return (ushort)((c.u + 0x7FFFu + ((c.u >> 16) & 1u)) >> 16);
}

// ---------------- bf16 MFMA GEMM: C = act(A @ Bt^T + bias) ----------------
// A: M x K bf16 row-major; Bt: N x K bf16 row-major; C: M x N fp32.
// 128x128 block tile, 4 waves (2x2), each wave 64x64 via 4x4 frags of 16x16x32.
template <int ACT, bool BIAS>
__global__ __launch_bounds__(256) void gemm_bf16(
    const ushort* __restrict__ A, const ushort* __restrict__ Bt,
    const float* __restrict__ bias, float* __restrict__ C, int M, int N, int K) {
  __shared__ __align__(16) ushort As[128][40];  // 32 + 8 pad (16B-aligned rows)
  __shared__ __align__(16) ushort Bs[128][40];
  const int tid = threadIdx.x;
  const int lane = tid & 63;
  const int w = tid >> 6;
  const int wr = (w >> 1) * 64, wc = (w & 1) * 64;
  const int fr = lane & 15;   // fragment row/col
  const int kg = lane >> 4;   // k-group: k = kg*8 .. kg*8+7
  const int bm = blockIdx.y * 128, bn = blockIdx.x * 128;
  // staging: 256 threads x 4 stores of 16B = 128 rows x 32 k, A and B.
  const int srow = tid >> 2, sg = tid & 3;
  const ushort* Asrc0 = A + (size_t)(bm + srow) * K + sg * 8;
  const ushort* Asrc1 = A + (size_t)(bm + srow + 64) * K + sg * 8;
  const ushort* Bsrc0 = Bt + (size_t)(bn + srow) * K + sg * 8;
  const ushort* Bsrc1 = Bt + (size_t)(bn + srow + 64) * K + sg * 8;

  f32x4 acc[4][4];
#pragma unroll
  for (int i = 0; i < 4; ++i)
#pragma unroll
    for (int j = 0; j < 4; ++j) acc[i][j] = (f32x4){0.f, 0.f, 0.f, 0.f};

  for (int k0 = 0; k0 < K; k0 += 32) {
    const uint4 a0 = *(const uint4*)(Asrc0 + k0);
    const uint4 a1 = *(const uint4*)(Asrc1 + k0);
    const uint4 b0 = *(const uint4*)(Bsrc0 + k0);
    const uint4 b1 = *(const uint4*)(Bsrc1 + k0);
    *(uint4*)&As[srow][sg * 8] = a0;
    *(uint4*)&As[srow + 64][sg * 8] = a1;
    *(uint4*)&Bs[srow][sg * 8] = b0;
    *(uint4*)&Bs[srow + 64][sg * 8] = b1;
    __syncthreads();
    bf16x8 a[4], b[4];
#pragma unroll
    for (int mi = 0; mi < 4; ++mi)
      a[mi] = *(const bf16x8*)&As[wr + mi * 16 + fr][kg * 8];
#pragma unroll
    for (int ni = 0; ni < 4; ++ni)
      b[ni] = *(const bf16x8*)&Bs[wc + ni * 16 + fr][kg * 8];
#pragma unroll
    for (int mi = 0; mi < 4; ++mi)
#pragma unroll
      for (int ni = 0; ni < 4; ++ni)
        acc[mi][ni] = __builtin_amdgcn_mfma_f32_16x16x32_bf16(
            a[mi], b[ni], acc[mi][ni], 0, 0, 0);
    __syncthreads();
  }

  float bv[4];
#pragma unroll
  for (int ni = 0; ni < 4; ++ni) bv[ni] = BIAS ? bias[bn + wc + ni * 16 + fr] : 0.f;
#pragma unroll
  for (int mi = 0; mi < 4; ++mi) {
#pragma unroll
    for (int i = 0; i < 4; ++i) {
      const int row = bm + wr + mi * 16 + kg * 4 + i;
      float* crow = &C[(size_t)row * N + bn + wc];
#pragma unroll
      for (int ni = 0; ni < 4; ++ni) {
        float v = acc[mi][ni][i] + bv[ni];
        if (ACT == ACT_RELU) v = fmaxf(v, 0.f);
        crow[ni * 16 + fr] = v;
      }
    }
  }
}

// ---------------- weight cast+transpose: W (KxN fp32) -> Wt (NxK bf16) ----
__global__ __launch_bounds__(256) void transpose_cast_k(
    const float* __restrict__ W, ushort* __restrict__ Wt, int K, int N) {
  __shared__ float t[32][33];
  const int tx = threadIdx.x & 31, ty = threadIdx.x >> 5;  // 32 x 8
  const int n0 = blockIdx.x * 32, k0 = blockIdx.y * 32;
#pragma unroll
  for (int i = 0; i < 32; i += 8)
    t[ty + i][tx] = W[(size_t)(k0 + ty + i) * N + n0 + tx];
  __syncthreads();
#pragma unroll
  for (int i = 0; i < 32; i += 8)
    Wt[(size_t)(n0 + ty + i) * K + k0 + tx] = f2bf(t[tx][ty + i]);
}

// ---------------- fp32 -> bf16 cast (8 elems/thread) ----------------------
__global__ __launch_bounds__(256) void cast_bf16_k(
    const float* __restrict__ x, ushort* __restrict__ y) {
  const size_t i = ((size_t)blockIdx.x * 256 + threadIdx.x) * 8;
  const float4 a = *(const float4*)&x[i];
  const float4 b = *(const float4*)&x[i + 4];
  ushort4 o0, o1;
  o0.x = f2bf(a.x); o0.y = f2bf(a.y); o0.z = f2bf(a.z); o0.w = f2bf(a.w);
  o1.x = f2bf(b.x); o1.y = f2bf(b.y); o1.z = f2bf(b.z); o1.w = f2bf(b.w);
  *(ushort4*)&y[i] = o0;
  *(ushort4*)&y[i + 4] = o1;
}

// ---------------- fp32 GEMM (kept for W_dt, K=32) -------------------------
template <int BM, int BN, int BK, int TM, int TN, int ACT, bool BIAS>
__global__ __launch_bounds__(256) void gemm_f32(
    const float* __restrict__ A, int lda, const float* __restrict__ B,
    const float* __restrict__ bias, float* __restrict__ C, int M, int N, int K) {
  constexpr int TX = BN / TN;
  constexpr int TY = BM / TM;
  static_assert(TX * TY == 256, "bad cfg");
  __shared__ float As[BK][BM + 4];
  __shared__ float Bs[BK][BN];
  const int tid = threadIdx.x;
  const int tx = tid % TX, ty = tid / TX;
  const int bm = blockIdx.y * BM, bn = blockIdx.x * BN;
  float acc[TM][TN];
#pragma unroll
  for (int i = 0; i < TM; ++i)
#pragma unroll
    for (int j = 0; j < TN; ++j) acc[i][j] = 0.f;

  for (int k0 = 0; k0 < K; k0 += BK) {
#pragma unroll
    for (int i = tid; i < BM * BK / 4; i += 256) {
      int r = i / (BK / 4), c4 = i % (BK / 4);
      const float4 v = *(const float4*)&A[(size_t)(bm + r) * lda + k0 + c4 * 4];
      As[c4 * 4 + 0][r] = v.x;
      As[c4 * 4 + 1][r] = v.y;
      As[c4 * 4 + 2][r] = v.z;
      As[c4 * 4 + 3][r] = v.w;
    }
#pragma unroll
    for (int i = tid; i < BK * BN / 4; i += 256) {
      int r = i / (BN / 4), c4 = i % (BN / 4);
      *(float4*)&Bs[r][c4 * 4] = *(const float4*)&B[(size_t)(k0 + r) * N + bn + c4 * 4];
    }
    __syncthreads();
#pragma unroll
    for (int k = 0; k < BK; ++k) {
      float a[TM], b[TN];
#pragma unroll
      for (int i = 0; i < TM; i += 4) {
        const float4 t = *(const float4*)&As[k][ty * TM + i];
        a[i] = t.x; a[i + 1] = t.y; a[i + 2] = t.z; a[i + 3] = t.w;
      }
#pragma unroll
      for (int j = 0; j < TN; j += 4) {
        const float4 t = *(const float4*)&Bs[k][tx * TN + j];
        b[j] = t.x; b[j + 1] = t.y; b[j + 2] = t.z; b[j + 3] = t.w;
      }
#pragma unroll
      for (int i = 0; i < TM; ++i)
#pragma unroll
        for (int j = 0; j < TN; ++j) acc[i][j] = fmaf(a[i], b[j], acc[i][j]);
    }
    __syncthreads();
  }
#pragma unroll
  for (int i = 0; i < TM; ++i) {
    const int row = bm + ty * TM + i;
#pragma unroll
    for (int j = 0; j < TN; ++j) {
      float v = acc[i][j];
      if (BIAS) v += bias[bn + tx * TN + j];
      if (ACT == ACT_RELU) v = fmaxf(v, 0.f);
      if (ACT == ACT_SOFTPLUS) v = fmaxf(v, 0.f) + log1pf(expf(-fabsf(v)));
      acc[i][j] = v;
    }
#pragma unroll
    for (int j = 0; j < TN; j += 4) {
      float4 t;
      t.x = acc[i][j]; t.y = acc[i][j + 1]; t.z = acc[i][j + 2]; t.w = acc[i][j + 3];
      *(float4*)&C[(size_t)row * N + bn + tx * TN + j] = t;
    }
  }
}

// ---------------- skinny GEMM for W_x: 4096x1024 @ 1024x64 ----------------
__global__ __launch_bounds__(256) void gemm_skinny64(
    const float* __restrict__ A, const float* __restrict__ B, float* __restrict__ C) {
  __shared__ float As[4][DINNER];
  const int r = threadIdx.x >> 6;
  const int j = threadIdx.x & 63;
  const int row0 = blockIdx.x * 4;
  for (int i = threadIdx.x; i < DINNER; i += 256) {
    *(float4*)&As[i >> 8][(i & 255) * 4] =
        *(const float4*)&A[(size_t)(row0 + (i >> 8)) * DINNER + (i & 255) * 4];
  }
  __syncthreads();
  float a0 = 0.f, a1 = 0.f, a2 = 0.f, a3 = 0.f;
  for (int k = 0; k < DINNER; k += 4) {
    a0 = fmaf(As[r][k + 0], B[(size_t)(k + 0) * 64 + j], a0);
    a1 = fmaf(As[r][k + 1], B[(size_t)(k + 1) * 64 + j], a1);
    a2 = fmaf(As[r][k + 2], B[(size_t)(k + 2) * 64 + j], a2);
    a3 = fmaf(As[r][k + 3], B[(size_t)(k + 3) * 64 + j], a3);
  }
  C[(size_t)(row0 + r) * 64 + j] = (a0 + a1) + (a2 + a3);
}

// ---------------- LayerNorm (512 cols); optional residual; fp32/bf16 out --
template <bool BF16OUT>
__global__ __launch_bounds__(256) void layernorm_k(
    const float* __restrict__ x, const float* __restrict__ res,
    const float* __restrict__ w, const float* __restrict__ b, void* __restrict__ outp) {
  const int wave = threadIdx.x >> 6, lane = threadIdx.x & 63;
  const int row = blockIdx.x * 4 + wave;
  const size_t base = (size_t)row * DMODEL;
  float4 v0 = *(const float4*)&x[base + lane * 4];
  float4 v1 = *(const float4*)&x[base + 256 + lane * 4];
  if (res != nullptr) {
    const float4 r0 = *(const float4*)&res[base + lane * 4];
    const float4 r1 = *(const float4*)&res[base + 256 + lane * 4];
    v0.x += r0.x; v0.y += r0.y; v0.z += r0.z; v0.w += r0.w;
    v1.x += r1.x; v1.y += r1.y; v1.z += r1.z; v1.w += r1.w;
  }
  float s = (v0.x + v0.y) + (v0.z + v0.w) + (v1.x + v1.y) + (v1.z + v1.w);
  const float mean = wave_sum(s) * (1.f / DMODEL);
  const float d0 = v0.x - mean, d1 = v0.y - mean, d2 = v0.z - mean, d3 = v0.w - mean;
  const float d4 = v1.x - mean, d5 = v1.y - mean, d6 = v1.z - mean, d7 = v1.w - mean;
  float q = (d0 * d0 + d1 * d1) + (d2 * d2 + d3 * d3) + (d4 * d4 + d5 * d5) + (d6 * d6 + d7 * d7);
  const float rstd = rsqrtf(wave_sum(q) * (1.f / DMODEL) + 1e-5f);
  const float4 w0 = *(const float4*)&w[lane * 4];
  const float4 w1 = *(const float4*)&w[256 + lane * 4];
  const float4 b0 = *(const float4*)&b[lane * 4];
  const float4 b1 = *(const float4*)&b[256 + lane * 4];
  float o0 = fmaf(d0 * rstd, w0.x, b0.x), o1 = fmaf(d1 * rstd, w0.y, b0.y);
  float o2 = fmaf(d2 * rstd, w0.z, b0.z), o3 = fmaf(d3 * rstd, w0.w, b0.w);
  float o4 = fmaf(d4 * rstd, w1.x, b1.x), o5 = fmaf(d5 * rstd, w1.y, b1.y);
  float o6 = fmaf(d6 * rstd, w1.z, b1.z), o7 = fmaf(d7 * rstd, w1.w, b1.w);
  if (BF16OUT) {
    ushort* out = (ushort*)outp;
    ushort4 u0, u1;
    u0.x = f2bf(o0); u0.y = f2bf(o1); u0.z = f2bf(o2); u0.w = f2bf(o3);
    u1.x = f2bf(o4); u1.y = f2bf(o5); u1.z = f2bf(o6); u1.w = f2bf(o7);
    *(ushort4*)&out[base + lane * 4] = u0;
    *(ushort4*)&out[base + 256 + lane * 4] = u1;
  } else {
    float* out = (float*)outp;
    float4 f0, f1;
    f0.x = o0; f0.y = o1; f0.z = o2; f0.w = o3;
    f1.x = o4; f1.y = o5; f1.z = o6; f1.w = o7;
    *(float4*)&out[base + lane * 4] = f0;
    *(float4*)&out[base + 256 + lane * 4] = f1;
  }
}

// ---------------- depthwise causal conv (D_CONV=4) + bias + silu ----------
__global__ __launch_bounds__(256) void conv_silu_k(
    const float* __restrict__ xz, const float* __restrict__ Wc,
    const float* __restrict__ bc, float* __restrict__ xc) {
  const int idx = blockIdx.x * 256 + threadIdx.x;
  const int d = idx & (DINNER - 1);
  const int t = idx >> 10;
  const float4 w = *(const float4*)&Wc[d * 4];
  float acc = bc[d];
  if (t >= 3) acc = fmaf(w.x, xz[(size_t)(t - 3) * 2 * DINNER + d], acc);
  if (t >= 2) acc = fmaf(w.y, xz[(size_t)(t - 2) * 2 * DINNER + d], acc);
  if (t >= 1) acc = fmaf(w.z, xz[(size_t)(t - 1) * 2 * DINNER + d], acc);
  acc = fmaf(w.w, xz[(size_t)t * 2 * DINNER + d], acc);
  xc[idx] = siluf(acc);
}

// ---------------- selective scan: 3-phase chunked linear recurrence -------
__global__ __launch_bounds__(256) void scan_phaseA(
    const float* __restrict__ delta, const float* __restrict__ xc,
    const float* __restrict__ xdbl, const float* __restrict__ A_log,
    float* __restrict__ chA, float* __restrict__ chB) {
  const int chunk = blockIdx.x >> 2;
  const int d = ((blockIdx.x & 3) << 8) + threadIdx.x;
  __shared__ float Bsh[CHLEN][DSTATE];
  for (int i = threadIdx.x; i < CHLEN * DSTATE; i += 256) {
    const int t = i >> 4, s = i & 15;
    Bsh[t][s] = xdbl[(size_t)(chunk * CHLEN + t) * 64 + 32 + s];
  }
  __syncthreads();
  float Av[DSTATE];
#pragma unroll
  for (int s = 0; s < DSTATE; ++s) Av[s] = -expf(A_log[d * DSTATE + s]);
  float aP[DSTATE], bP[DSTATE];
#pragma unroll
  for (int s = 0; s < DSTATE; ++s) { aP[s] = 1.f; bP[s] = 0.f; }
  for (int t = 0; t < CHLEN; ++t) {
    const int tt = chunk * CHLEN + t;
    const float dl = delta[(size_t)tt * DINNER + d];
    const float du = dl * xc[(size_t)tt * DINNER + d];
#pragma unroll
    for (int s = 0; s < DSTATE; ++s) {
      const float a = expf(dl * Av[s]);
      bP[s] = fmaf(a, bP[s], du * Bsh[t][s]);
      aP[s] *= a;
    }
  }
  const size_t base = (size_t)chunk * DINNER * DSTATE + (size_t)d * DSTATE;
#pragma unroll
  for (int s = 0; s < DSTATE; ++s) {
    chA[base + s] = aP[s];
    chB[base + s] = bP[s];
  }
}

__global__ __launch_bounds__(256) void scan_phaseB(
    const float* __restrict__ chA, const float* __restrict__ chB, float* __restrict__ s0) {
  const int i = blockIdx.x * 256 + threadIdx.x;
  float st = 0.f;
  for (int c = 0; c < NCHUNK; ++c) {
    const size_t idx = (size_t)c * DINNER * DSTATE + i;
    s0[idx] = st;
    st = fmaf(chA[idx], st, chB[idx]);
  }
}

__global__ __launch_bounds__(256) void scan_phaseC(
    const float* __restrict__ delta, const float* __restrict__ xc,
    const float* __restrict__ xdbl, const float* __restrict__ A_log,
    const float* __restrict__ Dsk, const float* __restrict__ s0,
    const float* __restrict__ xz, ushort* __restrict__ y) {
  const int chunk = blockIdx.x >> 2;
  const int d = ((blockIdx.x & 3) << 8) + threadIdx.x;
  __shared__ float BCsh[CHLEN][2 * DSTATE];
  for (int i = threadIdx.x; i < CHLEN * 2 * DSTATE; i += 256) {
    const int t = i >> 5, s = i & 31;
    BCsh[t][s] = xdbl[(size_t)(chunk * CHLEN + t) * 64 + 32 + s];
  }
  __syncthreads();
  float Av[DSTATE];
#pragma unroll
  for (int s = 0; s < DSTATE; ++s) Av[s] = -expf(A_log[d * DSTATE + s]);
  float st[DSTATE];
  const size_t base = (size_t)chunk * DINNER * DSTATE + (size_t)d * DSTATE;
#pragma unroll
  for (int s = 0; s < DSTATE; ++s) st[s] = s0[base + s];
  const float Dv = Dsk[d];
  for (int t = 0; t < CHLEN; ++t) {
    const int tt = chunk * CHLEN + t;
    const float dl = delta[(size_t)tt * DINNER + d];
    const float xv = xc[(size_t)tt * DINNER + d];
    const float du = dl * xv;
    float yv = 0.f;
#pragma unroll
    for (int s = 0; s < DSTATE; ++s) {
      const float a = expf(dl * Av[s]);
      st[s] = fmaf(a, st[s], du * BCsh[t][s]);
      yv = fmaf(st[s], BCsh[t][DSTATE + s], yv);
    }
    const float zv = xz[(size_t)tt * 2 * DINNER + DINNER + d];
    y[(size_t)tt * DINNER + d] = f2bf((yv + xv * Dv) * siluf(zv));
  }
}

// ---------------- attention scores: tanh(h@Wa1+ba1)@Wa2+ba2 ---------------
__global__ __launch_bounds__(128) void attn_scores_k(
    const float* __restrict__ h, const float* __restrict__ Wa1,
    const float* __restrict__ ba1, const float* __restrict__ Wa2,
    const float* __restrict__ ba2, float* __restrict__ scores) {
  __shared__ float hs[DMODEL];
  const int t = blockIdx.x;
  const int j = threadIdx.x;
  *(float4*)&hs[j * 4] = *(const float4*)&h[(size_t)t * DMODEL + j * 4];
  __syncthreads();
  float a0 = 0.f, a1 = 0.f, a2 = 0.f, a3 = 0.f;
  for (int k = 0; k < DMODEL; k += 4) {
    a0 = fmaf(hs[k + 0], Wa1[(size_t)(k + 0) * 128 + j], a0);
    a1 = fmaf(hs[k + 1], Wa1[(size_t)(k + 1) * 128 + j], a1);
    a2 = fmaf(hs[k + 2], Wa1[(size_t)(k + 2) * 128 + j], a2);
    a3 = fmaf(hs[k + 3], Wa1[(size_t)(k + 3) * 128 + j], a3);
  }
  float v = tanhf(((a0 + a1) + (a2 + a3)) + ba1[j]) * Wa2[j];
  v = wave_sum(v);
  __shared__ float red[2];
  if ((j & 63) == 0) red[j >> 6] = v;
  __syncthreads();
  if (j == 0) scores[t] = red[0] + red[1] + ba2[0];
}

__global__ __launch_bounds__(1024) void softmax_k(
    const float* __restrict__ s, float* __restrict__ aw) {
  const int tid = threadIdx.x;
  const int wave = tid >> 6, lane = tid & 63;
  const float4 v = *(const float4*)&s[tid * 4];
  float m = fmaxf(fmaxf(v.x, v.y), fmaxf(v.z, v.w));
  m = wave_max(m);
  __shared__ float redm[16];
  if (lane == 0) redm[wave] = m;
  __syncthreads();
  float bm = redm[0];
#pragma unroll
  for (int i = 1; i < 16; ++i) bm = fmaxf(bm, redm[i]);
  const float e0 = expf(v.x - bm), e1 = expf(v.y - bm);
  const float e2 = expf(v.z - bm), e3 = expf(v.w - bm);
  float sum = wave_sum((e0 + e1) + (e2 + e3));
  __shared__ float reds[16];
  if (lane == 0) reds[wave] = sum;
  __syncthreads();
  float Z = 0.f;
#pragma unroll
  for (int i = 0; i < 16; ++i) Z += reds[i];
  const float inv = 1.f / Z;
  float4 o;
  o.x = e0 * inv; o.y = e1 * inv; o.z = e2 * inv; o.w = e3 * inv;
  *(float4*)&aw[tid * 4] = o;
}

__global__ __launch_bounds__(256) void pool_partial_k(
    const float* __restrict__ aw, const float* __restrict__ h, float* __restrict__ part) {
  const int b = blockIdx.x;
  const int tid = threadIdx.x;
  float2 acc = make_float2(0.f, 0.f);
  for (int t = b * 64; t < b * 64 + 64; ++t) {
    const float w = aw[t];
    const float2 hv = *(const float2*)&h[(size_t)t * DMODEL + tid * 2];
    acc.x = fmaf(w, hv.x, acc.x);
    acc.y = fmaf(w, hv.y, acc.y);
  }
  *(float2*)&part[b * DMODEL + tid * 2] = acc;
}

__global__ __launch_bounds__(512) void pool_final_k(
    const float* __restrict__ part, const float* __restrict__ Wh,
    const float* __restrict__ bh, float* __restrict__ out) {
  const int d = threadIdx.x;
  float s = 0.f;
  for (int b = 0; b < 64; ++b) s += part[b * DMODEL + d];
  float v0 = wave_sum(s * Wh[d * 2 + 0]);
  float v1 = wave_sum(s * Wh[d * 2 + 1]);
  __shared__ float r0[8], r1[8];
  const int wave = d >> 6, lane = d & 63;
  if (lane == 0) { r0[wave] = v0; r1[wave] = v1; }
  __syncthreads();
  if (d == 0) {
    float o0 = bh[0], o1 = bh[1];
#pragma unroll
    for (int i = 0; i < 8; ++i) { o0 += r0[i]; o1 += r1[i]; }
    out[0] = o0;
    out[1] = o1;
  }
}

extern "C" void kernel_launch(void* const* d_in, const int* in_sizes, int n_in,
                              void* d_out, int out_size, void* d_ws, size_t ws_size,
                              hipStream_t stream) {
  const float* in_h = (const float*)d_in[0];
  const float* W_proj = (const float*)d_in[1];
  const float* b_proj = (const float*)d_in[2];
  const float* ln_w = (const float*)d_in[3];
  const float* ln_b = (const float*)d_in[4];
  const float* W_in = (const float*)d_in[5];
  const float* W_conv = (const float*)d_in[6];
  const float* b_conv = (const float*)d_in[7];
  const float* W_x = (const float*)d_in[8];
  const float* W_dt = (const float*)d_in[9];
  const float* b_dt = (const float*)d_in[10];
  const float* A_log = (const float*)d_in[11];
  const float* Dsk = (const float*)d_in[12];
  const float* W_out = (const float*)d_in[13];
  const float* norm_w = (const float*)d_in[14];
  const float* norm_b = (const float*)d_in[15];
  const float* Wa1 = (const float*)d_in[16];
  const float* ba1 = (const float*)d_in[17];
  const float* Wa2 = (const float*)d_in[18];
  const float* ba2 = (const float*)d_in[19];
  const float* Wh = (const float*)d_in[20];
  const float* bh = (const float*)d_in[21];
  float* out = (float*)d_out;

  float* ws = (float*)d_ws;
  size_t off = 0;
  auto alloc = [&](size_t n) {
    float* p = ws + off;
    off += (n + 63) & ~(size_t)63;
    return p;
  };
  float* res = alloc((size_t)LSEQ * DMODEL);
  float* hbuf = alloc((size_t)LSEQ * DMODEL);
  float* xz = alloc((size_t)LSEQ * 2 * DINNER);
  float* xc = alloc((size_t)LSEQ * DINNER);
  float* xdbl = alloc((size_t)LSEQ * 64);
  float* delta = alloc((size_t)LSEQ * DINNER);
  float* chA = alloc((size_t)DINNER * DSTATE * NCHUNK);
  float* chB = alloc((size_t)DINNER * DSTATE * NCHUNK);
  float* s0b = alloc((size_t)DINNER * DSTATE * NCHUNK);
  ushort* lnb_bf = (ushort*)alloc((size_t)LSEQ * DMODEL / 2);
  ushort* y_bf = (ushort*)alloc((size_t)LSEQ * DINNER / 2);
  ushort* in_bf = (ushort*)alloc((size_t)LSEQ * 1024 / 2);
  ushort* WprojT = (ushort*)alloc((size_t)DMODEL * 1024 / 2);
  (void)ws_size;
  // aliases (timeline-safe): weight transposes reuse in_bf after proj GEMM;
  // final-LN output + attn scratch reuse xz after last scan.
  ushort* W_inT = in_bf;                        // 2048*512 = 1M ushorts
  ushort* W_outT = in_bf + 2048 * 512;          // 512*1024 = 0.5M ushorts
  float* hfin = xz;                             // 4096*512
  float* scores = xz + (size_t)LSEQ * DMODEL;
  float* aw = scores + LSEQ;
  float* part = aw + LSEQ;

  // 1. cast input + transpose W_proj, then proj GEMM (relu+bias) -> res
  cast_bf16_k<<<(LSEQ * 1024) / (256 * 8), 256, 0, stream>>>(in_h, in_bf);
  transpose_cast_k<<<dim3(DMODEL / 32, 1024 / 32), 256, 0, stream>>>(
      W_proj, WprojT, 1024, DMODEL);
  gemm_bf16<ACT_RELU, true><<<dim3(DMODEL / 128, LSEQ / 128), 256, 0, stream>>>(
      in_bf, WprojT, b_proj, res, LSEQ, DMODEL, 1024);

  const float* cur = res;
  for (int l = 0; l < 2; ++l) {
    layernorm_k<true><<<LSEQ / 4, 256, 0, stream>>>(
        cur, nullptr, ln_w + l * DMODEL, ln_b + l * DMODEL, lnb_bf);
    transpose_cast_k<<<dim3(2 * DINNER / 32, DMODEL / 32), 256, 0, stream>>>(
        W_in + (size_t)l * DMODEL * 2 * DINNER, W_inT, DMODEL, 2 * DINNER);
    gemm_bf16<ACT_NONE, false>
        <<<dim3(2 * DINNER / 128, LSEQ / 128), 256, 0, stream>>>(
            lnb_bf, W_inT, nullptr, xz, LSEQ, 2 * DINNER, DMODEL);
    conv_silu_k<<<LSEQ * DINNER / 256, 256, 0, stream>>>(
        xz, W_conv + l * DINNER * 4, b_conv + l * DINNER, xc);
    gemm_skinny64<<<LSEQ / 4, 256, 0, stream>>>(
        xc, W_x + (size_t)l * DINNER * 64, xdbl);
    gemm_f32<128, 128, 16, 8, 8, ACT_SOFTPLUS, true>
        <<<dim3(DINNER / 128, LSEQ / 128), 256, 0, stream>>>(
            xdbl, 64, W_dt + (size_t)l * DTRANK * DINNER, b_dt + l * DINNER,
            delta, LSEQ, DINNER, DTRANK);
    const float* Al = A_log + (size_t)l * DINNER * DSTATE;
    scan_phaseA<<<NCHUNK * 4, 256, 0, stream>>>(delta, xc, xdbl, Al, chA, chB);
    scan_phaseB<<<DINNER * DSTATE / 256, 256, 0, stream>>>(chA, chB, s0b);
    scan_phaseC<<<NCHUNK * 4, 256, 0, stream>>>(
        delta, xc, xdbl, Al, Dsk + l * DINNER, s0b, xz, y_bf);
    transpose_cast_k<<<dim3(DMODEL / 32, DINNER / 32), 256, 0, stream>>>(
        W_out + (size_t)l * DINNER * DMODEL, W_outT, DINNER, DMODEL);
    gemm_bf16<ACT_NONE, false><<<dim3(DMODEL / 128, LSEQ / 128), 256, 0, stream>>>(
        y_bf, W_outT, nullptr, hbuf, LSEQ, DMODEL, DINNER);
    cur = hbuf;
  }

  layernorm_k<false><<<LSEQ / 4, 256, 0, stream>>>(cur, res, norm_w, norm_b, hfin);
  attn_scores_k<<<LSEQ, 128, 0, stream>>>(hfin, Wa1, ba1, Wa2, ba2, scores);
  softmax_k<<<1, 1024, 0, stream>>>(scores, aw);
  pool_partial_k<<<64, 256, 0, stream>>>(aw, hfin, part);
  pool_final_k<<<1, 512, 0, stream>>>(part, Wh, bh, out);
}

// Round 4
// 539.657 us; speedup vs baseline: 1.9054x; 1.1524x over previous
//
#include <hip/hip_runtime.h>
#include <math.h>

// MambaMIL: bf16-MFMA for the 3 big GEMMs (proj, W_in, W_out), fp32 elsewhere.
// R4: scan was latency-bound (74us/phase, 10.5% occupancy, 256 blocks).
//     NCHUNK 64->128 (512 blocks for phaseA/C), CHLEN 64->32, and 4-deep
//     load batching in the t-loop. No precision changes (absmax headroom 23%).

#define LSEQ 4096
#define DMODEL 512
#define DINNER 1024
#define DSTATE 16
#define DTRANK 32
#define NCHUNK 128
#define CHLEN 32

enum { ACT_NONE = 0, ACT_RELU = 1, ACT_SOFTPLUS = 2 };

typedef __attribute__((ext_vector_type(8))) short bf16x8;
typedef __attribute__((ext_vector_type(4))) float f32x4;

__device__ __forceinline__ float wave_sum(float v) {
#pragma unroll
  for (int off = 32; off > 0; off >>= 1) v += __shfl_xor(v, off, 64);
  return v;
}
__device__ __forceinline__ float wave_max(float v) {
#pragma unroll
  for (int off = 32; off > 0; off >>= 1) v = fmaxf(v, __shfl_xor(v, off, 64));
  return v;
}
__device__ __forceinline__ float siluf(float x) { return x / (1.f + expf(-x)); }

__device__ __forceinline__ ushort f2bf(float f) {
  union { float f; unsigned u; } c;
  c.f = f;
  return (ushort)((c.u + 0x7FFFu + ((c.u >> 16) & 1u)) >> 16);
}

// ---------------- bf16 MFMA GEMM: C = act(A @ Bt^T + bias) ----------------
// A: M x K bf16 row-major; Bt: N x K bf16 row-major; C: M x N fp32.
// 128x128 block tile, 4 waves (2x2), each wave 64x64 via 4x4 frags of 16x16x32.
template <int ACT, bool BIAS>
__global__ __launch_bounds__(256) void gemm_bf16(
    const ushort* __restrict__ A, const ushort* __restrict__ Bt,
    const float* __restrict__ bias, float* __restrict__ C, int M, int N, int K) {
  __shared__ __align__(16) ushort As[128][40];  // 32 + 8 pad (16B-aligned rows)
  __shared__ __align__(16) ushort Bs[128][40];
  const int tid = threadIdx.x;
  const int lane = tid & 63;
  const int w = tid >> 6;
  const int wr = (w >> 1) * 64, wc = (w & 1) * 64;
  const int fr = lane & 15;   // fragment row/col
  const int kg = lane >> 4;   // k-group: k = kg*8 .. kg*8+7
  const int bm = blockIdx.y * 128, bn = blockIdx.x * 128;
  // staging: 256 threads x 4 stores of 16B = 128 rows x 32 k, A and B.
  const int srow = tid >> 2, sg = tid & 3;
  const ushort* Asrc0 = A + (size_t)(bm + srow) * K + sg * 8;
  const ushort* Asrc1 = A + (size_t)(bm + srow + 64) * K + sg * 8;
  const ushort* Bsrc0 = Bt + (size_t)(bn + srow) * K + sg * 8;
  const ushort* Bsrc1 = Bt + (size_t)(bn + srow + 64) * K + sg * 8;

  f32x4 acc[4][4];
#pragma unroll
  for (int i = 0; i < 4; ++i)
#pragma unroll
    for (int j = 0; j < 4; ++j) acc[i][j] = (f32x4){0.f, 0.f, 0.f, 0.f};

  for (int k0 = 0; k0 < K; k0 += 32) {
    const uint4 a0 = *(const uint4*)(Asrc0 + k0);
    const uint4 a1 = *(const uint4*)(Asrc1 + k0);
    const uint4 b0 = *(const uint4*)(Bsrc0 + k0);
    const uint4 b1 = *(const uint4*)(Bsrc1 + k0);
    *(uint4*)&As[srow][sg * 8] = a0;
    *(uint4*)&As[srow + 64][sg * 8] = a1;
    *(uint4*)&Bs[srow][sg * 8] = b0;
    *(uint4*)&Bs[srow + 64][sg * 8] = b1;
    __syncthreads();
    bf16x8 a[4], b[4];
#pragma unroll
    for (int mi = 0; mi < 4; ++mi)
      a[mi] = *(const bf16x8*)&As[wr + mi * 16 + fr][kg * 8];
#pragma unroll
    for (int ni = 0; ni < 4; ++ni)
      b[ni] = *(const bf16x8*)&Bs[wc + ni * 16 + fr][kg * 8];
#pragma unroll
    for (int mi = 0; mi < 4; ++mi)
#pragma unroll
      for (int ni = 0; ni < 4; ++ni)
        acc[mi][ni] = __builtin_amdgcn_mfma_f32_16x16x32_bf16(
            a[mi], b[ni], acc[mi][ni], 0, 0, 0);
    __syncthreads();
  }

  float bv[4];
#pragma unroll
  for (int ni = 0; ni < 4; ++ni) bv[ni] = BIAS ? bias[bn + wc + ni * 16 + fr] : 0.f;
#pragma unroll
  for (int mi = 0; mi < 4; ++mi) {
#pragma unroll
    for (int i = 0; i < 4; ++i) {
      const int row = bm + wr + mi * 16 + kg * 4 + i;
      float* crow = &C[(size_t)row * N + bn + wc];
#pragma unroll
      for (int ni = 0; ni < 4; ++ni) {
        float v = acc[mi][ni][i] + bv[ni];
        if (ACT == ACT_RELU) v = fmaxf(v, 0.f);
        crow[ni * 16 + fr] = v;
      }
    }
  }
}

// ---------------- weight cast+transpose: W (KxN fp32) -> Wt (NxK bf16) ----
__global__ __launch_bounds__(256) void transpose_cast_k(
    const float* __restrict__ W, ushort* __restrict__ Wt, int K, int N) {
  __shared__ float t[32][33];
  const int tx = threadIdx.x & 31, ty = threadIdx.x >> 5;  // 32 x 8
  const int n0 = blockIdx.x * 32, k0 = blockIdx.y * 32;
#pragma unroll
  for (int i = 0; i < 32; i += 8)
    t[ty + i][tx] = W[(size_t)(k0 + ty + i) * N + n0 + tx];
  __syncthreads();
#pragma unroll
  for (int i = 0; i < 32; i += 8)
    Wt[(size_t)(n0 + ty + i) * K + k0 + tx] = f2bf(t[tx][ty + i]);
}

// ---------------- fp32 -> bf16 cast (8 elems/thread) ----------------------
__global__ __launch_bounds__(256) void cast_bf16_k(
    const float* __restrict__ x, ushort* __restrict__ y) {
  const size_t i = ((size_t)blockIdx.x * 256 + threadIdx.x) * 8;
  const float4 a = *(const float4*)&x[i];
  const float4 b = *(const float4*)&x[i + 4];
  ushort4 o0, o1;
  o0.x = f2bf(a.x); o0.y = f2bf(a.y); o0.z = f2bf(a.z); o0.w = f2bf(a.w);
  o1.x = f2bf(b.x); o1.y = f2bf(b.y); o1.z = f2bf(b.z); o1.w = f2bf(b.w);
  *(ushort4*)&y[i] = o0;
  *(ushort4*)&y[i + 4] = o1;
}

// ---------------- fp32 GEMM (kept for W_dt, K=32) -------------------------
template <int BM, int BN, int BK, int TM, int TN, int ACT, bool BIAS>
__global__ __launch_bounds__(256) void gemm_f32(
    const float* __restrict__ A, int lda, const float* __restrict__ B,
    const float* __restrict__ bias, float* __restrict__ C, int M, int N, int K) {
  constexpr int TX = BN / TN;
  constexpr int TY = BM / TM;
  static_assert(TX * TY == 256, "bad cfg");
  __shared__ float As[BK][BM + 4];
  __shared__ float Bs[BK][BN];
  const int tid = threadIdx.x;
  const int tx = tid % TX, ty = tid / TX;
  const int bm = blockIdx.y * BM, bn = blockIdx.x * BN;
  float acc[TM][TN];
#pragma unroll
  for (int i = 0; i < TM; ++i)
#pragma unroll
    for (int j = 0; j < TN; ++j) acc[i][j] = 0.f;

  for (int k0 = 0; k0 < K; k0 += BK) {
#pragma unroll
    for (int i = tid; i < BM * BK / 4; i += 256) {
      int r = i / (BK / 4), c4 = i % (BK / 4);
      const float4 v = *(const float4*)&A[(size_t)(bm + r) * lda + k0 + c4 * 4];
      As[c4 * 4 + 0][r] = v.x;
      As[c4 * 4 + 1][r] = v.y;
      As[c4 * 4 + 2][r] = v.z;
      As[c4 * 4 + 3][r] = v.w;
    }
#pragma unroll
    for (int i = tid; i < BK * BN / 4; i += 256) {
      int r = i / (BN / 4), c4 = i % (BN / 4);
      *(float4*)&Bs[r][c4 * 4] = *(const float4*)&B[(size_t)(k0 + r) * N + bn + c4 * 4];
    }
    __syncthreads();
#pragma unroll
    for (int k = 0; k < BK; ++k) {
      float a[TM], b[TN];
#pragma unroll
      for (int i = 0; i < TM; i += 4) {
        const float4 t = *(const float4*)&As[k][ty * TM + i];
        a[i] = t.x; a[i + 1] = t.y; a[i + 2] = t.z; a[i + 3] = t.w;
      }
#pragma unroll
      for (int j = 0; j < TN; j += 4) {
        const float4 t = *(const float4*)&Bs[k][tx * TN + j];
        b[j] = t.x; b[j + 1] = t.y; b[j + 2] = t.z; b[j + 3] = t.w;
      }
#pragma unroll
      for (int i = 0; i < TM; ++i)
#pragma unroll
        for (int j = 0; j < TN; ++j) acc[i][j] = fmaf(a[i], b[j], acc[i][j]);
    }
    __syncthreads();
  }
#pragma unroll
  for (int i = 0; i < TM; ++i) {
    const int row = bm + ty * TM + i;
#pragma unroll
    for (int j = 0; j < TN; ++j) {
      float v = acc[i][j];
      if (BIAS) v += bias[bn + tx * TN + j];
      if (ACT == ACT_RELU) v = fmaxf(v, 0.f);
      if (ACT == ACT_SOFTPLUS) v = fmaxf(v, 0.f) + log1pf(expf(-fabsf(v)));
      acc[i][j] = v;
    }
#pragma unroll
    for (int j = 0; j < TN; j += 4) {
      float4 t;
      t.x = acc[i][j]; t.y = acc[i][j + 1]; t.z = acc[i][j + 2]; t.w = acc[i][j + 3];
      *(float4*)&C[(size_t)row * N + bn + tx * TN + j] = t;
    }
  }
}

// ---------------- skinny GEMM for W_x: 4096x1024 @ 1024x64 ----------------
__global__ __launch_bounds__(256) void gemm_skinny64(
    const float* __restrict__ A, const float* __restrict__ B, float* __restrict__ C) {
  __shared__ float As[4][DINNER];
  const int r = threadIdx.x >> 6;
  const int j = threadIdx.x & 63;
  const int row0 = blockIdx.x * 4;
  for (int i = threadIdx.x; i < DINNER; i += 256) {
    *(float4*)&As[i >> 8][(i & 255) * 4] =
        *(const float4*)&A[(size_t)(row0 + (i >> 8)) * DINNER + (i & 255) * 4];
  }
  __syncthreads();
  float a0 = 0.f, a1 = 0.f, a2 = 0.f, a3 = 0.f;
  for (int k = 0; k < DINNER; k += 4) {
    a0 = fmaf(As[r][k + 0], B[(size_t)(k + 0) * 64 + j], a0);
    a1 = fmaf(As[r][k + 1], B[(size_t)(k + 1) * 64 + j], a1);
    a2 = fmaf(As[r][k + 2], B[(size_t)(k + 2) * 64 + j], a2);
    a3 = fmaf(As[r][k + 3], B[(size_t)(k + 3) * 64 + j], a3);
  }
  C[(size_t)(row0 + r) * 64 + j] = (a0 + a1) + (a2 + a3);
}

// ---------------- LayerNorm (512 cols); optional residual; fp32/bf16 out --
template <bool BF16OUT>
__global__ __launch_bounds__(256) void layernorm_k(
    const float* __restrict__ x, const float* __restrict__ res,
    const float* __restrict__ w, const float* __restrict__ b, void* __restrict__ outp) {
  const int wave = threadIdx.x >> 6, lane = threadIdx.x & 63;
  const int row = blockIdx.x * 4 + wave;
  const size_t base = (size_t)row * DMODEL;
  float4 v0 = *(const float4*)&x[base + lane * 4];
  float4 v1 = *(const float4*)&x[base + 256 + lane * 4];
  if (res != nullptr) {
    const float4 r0 = *(const float4*)&res[base + lane * 4];
    const float4 r1 = *(const float4*)&res[base + 256 + lane * 4];
    v0.x += r0.x; v0.y += r0.y; v0.z += r0.z; v0.w += r0.w;
    v1.x += r1.x; v1.y += r1.y; v1.z += r1.z; v1.w += r1.w;
  }
  float s = (v0.x + v0.y) + (v0.z + v0.w) + (v1.x + v1.y) + (v1.z + v1.w);
  const float mean = wave_sum(s) * (1.f / DMODEL);
  const float d0 = v0.x - mean, d1 = v0.y - mean, d2 = v0.z - mean, d3 = v0.w - mean;
  const float d4 = v1.x - mean, d5 = v1.y - mean, d6 = v1.z - mean, d7 = v1.w - mean;
  float q = (d0 * d0 + d1 * d1) + (d2 * d2 + d3 * d3) + (d4 * d4 + d5 * d5) + (d6 * d6 + d7 * d7);
  const float rstd = rsqrtf(wave_sum(q) * (1.f / DMODEL) + 1e-5f);
  const float4 w0 = *(const float4*)&w[lane * 4];
  const float4 w1 = *(const float4*)&w[256 + lane * 4];
  const float4 b0 = *(const float4*)&b[lane * 4];
  const float4 b1 = *(const float4*)&b[256 + lane * 4];
  float o0 = fmaf(d0 * rstd, w0.x, b0.x), o1 = fmaf(d1 * rstd, w0.y, b0.y);
  float o2 = fmaf(d2 * rstd, w0.z, b0.z), o3 = fmaf(d3 * rstd, w0.w, b0.w);
  float o4 = fmaf(d4 * rstd, w1.x, b1.x), o5 = fmaf(d5 * rstd, w1.y, b1.y);
  float o6 = fmaf(d6 * rstd, w1.z, b1.z), o7 = fmaf(d7 * rstd, w1.w, b1.w);
  if (BF16OUT) {
    ushort* out = (ushort*)outp;
    ushort4 u0, u1;
    u0.x = f2bf(o0); u0.y = f2bf(o1); u0.z = f2bf(o2); u0.w = f2bf(o3);
    u1.x = f2bf(o4); u1.y = f2bf(o5); u1.z = f2bf(o6); u1.w = f2bf(o7);
    *(ushort4*)&out[base + lane * 4] = u0;
    *(ushort4*)&out[base + 256 + lane * 4] = u1;
  } else {
    float* out = (float*)outp;
    float4 f0, f1;
    f0.x = o0; f0.y = o1; f0.z = o2; f0.w = o3;
    f1.x = o4; f1.y = o5; f1.z = o6; f1.w = o7;
    *(float4*)&out[base + lane * 4] = f0;
    *(float4*)&out[base + 256 + lane * 4] = f1;
  }
}

// ---------------- depthwise causal conv (D_CONV=4) + bias + silu ----------
__global__ __launch_bounds__(256) void conv_silu_k(
    const float* __restrict__ xz, const float* __restrict__ Wc,
    const float* __restrict__ bc, float* __restrict__ xc) {
  const int idx = blockIdx.x * 256 + threadIdx.x;
  const int d = idx & (DINNER - 1);
  const int t = idx >> 10;
  const float4 w = *(const float4*)&Wc[d * 4];
  float acc = bc[d];
  if (t >= 3) acc = fmaf(w.x, xz[(size_t)(t - 3) * 2 * DINNER + d], acc);
  if (t >= 2) acc = fmaf(w.y, xz[(size_t)(t - 2) * 2 * DINNER + d], acc);
  if (t >= 1) acc = fmaf(w.z, xz[(size_t)(t - 1) * 2 * DINNER + d], acc);
  acc = fmaf(w.w, xz[(size_t)t * 2 * DINNER + d], acc);
  xc[idx] = siluf(acc);
}

// ---------------- selective scan: 3-phase chunked linear recurrence -------
// Per (d,s): state' = exp(delta*A[d,s]) * state + delta*B[t,s]*x[t,d]
__global__ __launch_bounds__(256) void scan_phaseA(
    const float* __restrict__ delta, const float* __restrict__ xc,
    const float* __restrict__ xdbl, const float* __restrict__ A_log,
    float* __restrict__ chA, float* __restrict__ chB) {
  const int chunk = blockIdx.x >> 2;
  const int d = ((blockIdx.x & 3) << 8) + threadIdx.x;
  __shared__ float Bsh[CHLEN][DSTATE];
  for (int i = threadIdx.x; i < CHLEN * DSTATE; i += 256) {
    const int t = i >> 4, s = i & 15;
    Bsh[t][s] = xdbl[(size_t)(chunk * CHLEN + t) * 64 + 32 + s];
  }
  __syncthreads();
  float Av[DSTATE];
#pragma unroll
  for (int s = 0; s < DSTATE; ++s) Av[s] = -expf(A_log[d * DSTATE + s]);
  float aP[DSTATE], bP[DSTATE];
#pragma unroll
  for (int s = 0; s < DSTATE; ++s) { aP[s] = 1.f; bP[s] = 0.f; }
  const size_t col = (size_t)chunk * CHLEN * DINNER + d;
  for (int t0 = 0; t0 < CHLEN; t0 += 4) {
    float dl[4], du[4];
#pragma unroll
    for (int u = 0; u < 4; ++u) {
      const size_t idx = col + (size_t)(t0 + u) * DINNER;
      dl[u] = delta[idx];
      du[u] = dl[u] * xc[idx];
    }
#pragma unroll
    for (int u = 0; u < 4; ++u) {
#pragma unroll
      for (int s = 0; s < DSTATE; ++s) {
        const float a = expf(dl[u] * Av[s]);
        bP[s] = fmaf(a, bP[s], du[u] * Bsh[t0 + u][s]);
        aP[s] *= a;
      }
    }
  }
  const size_t base = (size_t)chunk * DINNER * DSTATE + (size_t)d * DSTATE;
#pragma unroll
  for (int s = 0; s < DSTATE; ++s) {
    chA[base + s] = aP[s];
    chB[base + s] = bP[s];
  }
}

__global__ __launch_bounds__(256) void scan_phaseB(
    const float* __restrict__ chA, const float* __restrict__ chB, float* __restrict__ s0) {
  const int i = blockIdx.x * 256 + threadIdx.x;  // = d*16 + s
  float st = 0.f;
  for (int c = 0; c < NCHUNK; ++c) {
    const size_t idx = (size_t)c * DINNER * DSTATE + i;
    s0[idx] = st;
    st = fmaf(chA[idx], st, chB[idx]);
  }
}

__global__ __launch_bounds__(256) void scan_phaseC(
    const float* __restrict__ delta, const float* __restrict__ xc,
    const float* __restrict__ xdbl, const float* __restrict__ A_log,
    const float* __restrict__ Dsk, const float* __restrict__ s0,
    const float* __restrict__ xz, ushort* __restrict__ y) {
  const int chunk = blockIdx.x >> 2;
  const int d = ((blockIdx.x & 3) << 8) + threadIdx.x;
  __shared__ float BCsh[CHLEN][2 * DSTATE];
  for (int i = threadIdx.x; i < CHLEN * 2 * DSTATE; i += 256) {
    const int t = i >> 5, s = i & 31;
    BCsh[t][s] = xdbl[(size_t)(chunk * CHLEN + t) * 64 + 32 + s];
  }
  __syncthreads();
  float Av[DSTATE];
#pragma unroll
  for (int s = 0; s < DSTATE; ++s) Av[s] = -expf(A_log[d * DSTATE + s]);
  float st[DSTATE];
  const size_t base = (size_t)chunk * DINNER * DSTATE + (size_t)d * DSTATE;
#pragma unroll
  for (int s = 0; s < DSTATE; ++s) st[s] = s0[base + s];
  const float Dv = Dsk[d];
  const size_t col = (size_t)chunk * CHLEN * DINNER + d;
  const size_t zcol = (size_t)chunk * CHLEN * 2 * DINNER + DINNER + d;
  for (int t0 = 0; t0 < CHLEN; t0 += 4) {
    float dl[4], xv[4], zv[4];
#pragma unroll
    for (int u = 0; u < 4; ++u) {
      const size_t idx = col + (size_t)(t0 + u) * DINNER;
      dl[u] = delta[idx];
      xv[u] = xc[idx];
      zv[u] = xz[zcol + (size_t)(t0 + u) * 2 * DINNER];
    }
    ushort yo[4];
#pragma unroll
    for (int u = 0; u < 4; ++u) {
      const float du = dl[u] * xv[u];
      float yv = 0.f;
#pragma unroll
      for (int s = 0; s < DSTATE; ++s) {
        const float a = expf(dl[u] * Av[s]);
        st[s] = fmaf(a, st[s], du * BCsh[t0 + u][s]);
        yv = fmaf(st[s], BCsh[t0 + u][DSTATE + s], yv);
      }
      yo[u] = f2bf((yv + xv[u] * Dv) * siluf(zv[u]));
    }
#pragma unroll
    for (int u = 0; u < 4; ++u)
      y[col + (size_t)(t0 + u) * DINNER] = yo[u];
  }
}

// ---------------- attention scores: tanh(h@Wa1+ba1)@Wa2+ba2 ---------------
__global__ __launch_bounds__(128) void attn_scores_k(
    const float* __restrict__ h, const float* __restrict__ Wa1,
    const float* __restrict__ ba1, const float* __restrict__ Wa2,
    const float* __restrict__ ba2, float* __restrict__ scores) {
  __shared__ float hs[DMODEL];
  const int t = blockIdx.x;
  const int j = threadIdx.x;
  *(float4*)&hs[j * 4] = *(const float4*)&h[(size_t)t * DMODEL + j * 4];
  __syncthreads();
  float a0 = 0.f, a1 = 0.f, a2 = 0.f, a3 = 0.f;
  for (int k = 0; k < DMODEL; k += 4) {
    a0 = fmaf(hs[k + 0], Wa1[(size_t)(k + 0) * 128 + j], a0);
    a1 = fmaf(hs[k + 1], Wa1[(size_t)(k + 1) * 128 + j], a1);
    a2 = fmaf(hs[k + 2], Wa1[(size_t)(k + 2) * 128 + j], a2);
    a3 = fmaf(hs[k + 3], Wa1[(size_t)(k + 3) * 128 + j], a3);
  }
  float v = tanhf(((a0 + a1) + (a2 + a3)) + ba1[j]) * Wa2[j];
  v = wave_sum(v);
  __shared__ float red[2];
  if ((j & 63) == 0) red[j >> 6] = v;
  __syncthreads();
  if (j == 0) scores[t] = red[0] + red[1] + ba2[0];
}

__global__ __launch_bounds__(1024) void softmax_k(
    const float* __restrict__ s, float* __restrict__ aw) {
  const int tid = threadIdx.x;
  const int wave = tid >> 6, lane = tid & 63;
  const float4 v = *(const float4*)&s[tid * 4];
  float m = fmaxf(fmaxf(v.x, v.y), fmaxf(v.z, v.w));
  m = wave_max(m);
  __shared__ float redm[16];
  if (lane == 0) redm[wave] = m;
  __syncthreads();
  float bm = redm[0];
#pragma unroll
  for (int i = 1; i < 16; ++i) bm = fmaxf(bm, redm[i]);
  const float e0 = expf(v.x - bm), e1 = expf(v.y - bm);
  const float e2 = expf(v.z - bm), e3 = expf(v.w - bm);
  float sum = wave_sum((e0 + e1) + (e2 + e3));
  __shared__ float reds[16];
  if (lane == 0) reds[wave] = sum;
  __syncthreads();
  float Z = 0.f;
#pragma unroll
  for (int i = 0; i < 16; ++i) Z += reds[i];
  const float inv = 1.f / Z;
  float4 o;
  o.x = e0 * inv; o.y = e1 * inv; o.z = e2 * inv; o.w = e3 * inv;
  *(float4*)&aw[tid * 4] = o;
}

__global__ __launch_bounds__(256) void pool_partial_k(
    const float* __restrict__ aw, const float* __restrict__ h, float* __restrict__ part) {
  const int b = blockIdx.x;
  const int tid = threadIdx.x;
  float2 acc = make_float2(0.f, 0.f);
  for (int t = b * 64; t < b * 64 + 64; ++t) {
    const float w = aw[t];
    const float2 hv = *(const float2*)&h[(size_t)t * DMODEL + tid * 2];
    acc.x = fmaf(w, hv.x, acc.x);
    acc.y = fmaf(w, hv.y, acc.y);
  }
  *(float2*)&part[b * DMODEL + tid * 2] = acc;
}

__global__ __launch_bounds__(512) void pool_final_k(
    const float* __restrict__ part, const float* __restrict__ Wh,
    const float* __restrict__ bh, float* __restrict__ out) {
  const int d = threadIdx.x;
  float s = 0.f;
  for (int b = 0; b < 64; ++b) s += part[b * DMODEL + d];
  float v0 = wave_sum(s * Wh[d * 2 + 0]);
  float v1 = wave_sum(s * Wh[d * 2 + 1]);
  __shared__ float r0[8], r1[8];
  const int wave = d >> 6, lane = d & 63;
  if (lane == 0) { r0[wave] = v0; r1[wave] = v1; }
  __syncthreads();
  if (d == 0) {
    float o0 = bh[0], o1 = bh[1];
#pragma unroll
    for (int i = 0; i < 8; ++i) { o0 += r0[i]; o1 += r1[i]; }
    out[0] = o0;
    out[1] = o1;
  }
}

extern "C" void kernel_launch(void* const* d_in, const int* in_sizes, int n_in,
                              void* d_out, int out_size, void* d_ws, size_t ws_size,
                              hipStream_t stream) {
  const float* in_h = (const float*)d_in[0];
  const float* W_proj = (const float*)d_in[1];
  const float* b_proj = (const float*)d_in[2];
  const float* ln_w = (const float*)d_in[3];
  const float* ln_b = (const float*)d_in[4];
  const float* W_in = (const float*)d_in[5];
  const float* W_conv = (const float*)d_in[6];
  const float* b_conv = (const float*)d_in[7];
  const float* W_x = (const float*)d_in[8];
  const float* W_dt = (const float*)d_in[9];
  const float* b_dt = (const float*)d_in[10];
  const float* A_log = (const float*)d_in[11];
  const float* Dsk = (const float*)d_in[12];
  const float* W_out = (const float*)d_in[13];
  const float* norm_w = (const float*)d_in[14];
  const float* norm_b = (const float*)d_in[15];
  const float* Wa1 = (const float*)d_in[16];
  const float* ba1 = (const float*)d_in[17];
  const float* Wa2 = (const float*)d_in[18];
  const float* ba2 = (const float*)d_in[19];
  const float* Wh = (const float*)d_in[20];
  const float* bh = (const float*)d_in[21];
  float* out = (float*)d_out;

  float* ws = (float*)d_ws;
  size_t off = 0;
  auto alloc = [&](size_t n) {
    float* p = ws + off;
    off += (n + 63) & ~(size_t)63;
    return p;
  };
  float* res = alloc((size_t)LSEQ * DMODEL);
  float* hbuf = alloc((size_t)LSEQ * DMODEL);
  float* xz = alloc((size_t)LSEQ * 2 * DINNER);
  float* xc = alloc((size_t)LSEQ * DINNER);
  float* xdbl = alloc((size_t)LSEQ * 64);
  float* delta = alloc((size_t)LSEQ * DINNER);
  float* chA = alloc((size_t)DINNER * DSTATE * NCHUNK);
  float* chB = alloc((size_t)DINNER * DSTATE * NCHUNK);
  float* s0b = alloc((size_t)DINNER * DSTATE * NCHUNK);
  ushort* lnb_bf = (ushort*)alloc((size_t)LSEQ * DMODEL / 2);
  ushort* y_bf = (ushort*)alloc((size_t)LSEQ * DINNER / 2);
  ushort* in_bf = (ushort*)alloc((size_t)LSEQ * 1024 / 2);
  ushort* WprojT = (ushort*)alloc((size_t)DMODEL * 1024 / 2);
  (void)ws_size;
  // aliases (timeline-safe): weight transposes reuse in_bf after proj GEMM;
  // final-LN output + attn scratch reuse xz after last scan.
  ushort* W_inT = in_bf;                        // 2048*512 = 1M ushorts
  ushort* W_outT = in_bf + 2048 * 512;          // 512*1024 = 0.5M ushorts
  float* hfin = xz;                             // 4096*512
  float* scores = xz + (size_t)LSEQ * DMODEL;
  float* aw = scores + LSEQ;
  float* part = aw + LSEQ;

  // 1. cast input + transpose W_proj, then proj GEMM (relu+bias) -> res
  cast_bf16_k<<<(LSEQ * 1024) / (256 * 8), 256, 0, stream>>>(in_h, in_bf);
  transpose_cast_k<<<dim3(DMODEL / 32, 1024 / 32), 256, 0, stream>>>(
      W_proj, WprojT, 1024, DMODEL);
  gemm_bf16<ACT_RELU, true><<<dim3(DMODEL / 128, LSEQ / 128), 256, 0, stream>>>(
      in_bf, WprojT, b_proj, res, LSEQ, DMODEL, 1024);

  const float* cur = res;
  for (int l = 0; l < 2; ++l) {
    layernorm_k<true><<<LSEQ / 4, 256, 0, stream>>>(
        cur, nullptr, ln_w + l * DMODEL, ln_b + l * DMODEL, lnb_bf);
    transpose_cast_k<<<dim3(2 * DINNER / 32, DMODEL / 32), 256, 0, stream>>>(
        W_in + (size_t)l * DMODEL * 2 * DINNER, W_inT, DMODEL, 2 * DINNER);
    gemm_bf16<ACT_NONE, false>
        <<<dim3(2 * DINNER / 128, LSEQ / 128), 256, 0, stream>>>(
            lnb_bf, W_inT, nullptr, xz, LSEQ, 2 * DINNER, DMODEL);
    conv_silu_k<<<LSEQ * DINNER / 256, 256, 0, stream>>>(
        xz, W_conv + l * DINNER * 4, b_conv + l * DINNER, xc);
    gemm_skinny64<<<LSEQ / 4, 256, 0, stream>>>(
        xc, W_x + (size_t)l * DINNER * 64, xdbl);
    gemm_f32<128, 128, 16, 8, 8, ACT_SOFTPLUS, true>
        <<<dim3(DINNER / 128, LSEQ / 128), 256, 0, stream>>>(
            xdbl, 64, W_dt + (size_t)l * DTRANK * DINNER, b_dt + l * DINNER,
            delta, LSEQ, DINNER, DTRANK);
    const float* Al = A_log + (size_t)l * DINNER * DSTATE;
    scan_phaseA<<<NCHUNK * 4, 256, 0, stream>>>(delta, xc, xdbl, Al, chA, chB);
    scan_phaseB<<<DINNER * DSTATE / 256, 256, 0, stream>>>(chA, chB, s0b);
    scan_phaseC<<<NCHUNK * 4, 256, 0, stream>>>(
        delta, xc, xdbl, Al, Dsk + l * DINNER, s0b, xz, y_bf);
    transpose_cast_k<<<dim3(DMODEL / 32, DINNER / 32), 256, 0, stream>>>(
        W_out + (size_t)l * DINNER * DMODEL, W_outT, DINNER, DMODEL);
    gemm_bf16<ACT_NONE, false><<<dim3(DMODEL / 128, LSEQ / 128), 256, 0, stream>>>(
        y_bf, W_outT, nullptr, hbuf, LSEQ, DMODEL, DINNER);
    cur = hbuf;
  }

  layernorm_k<false><<<LSEQ / 4, 256, 0, stream>>>(cur, res, norm_w, norm_b, hfin);
  attn_scores_k<<<LSEQ, 128, 0, stream>>>(hfin, Wa1, ba1, Wa2, ba2, scores);
  softmax_k<<<1, 1024, 0, stream>>>(scores, aw);
  pool_partial_k<<<64, 256, 0, stream>>>(aw, hfin, part);
  pool_final_k<<<1, 512, 0, stream>>>(part, Wh, bh, out);
}